// Round 5
// baseline (635.929 us; speedup 1.0000x reference)
//
#include <hip/hip_runtime.h>
#include <math.h>

#define B_   16
#define S_   1056
#define SP_  1088             // k padded to 34*32
#define DM_  256
#define H_   8
#define DK_  32
#define TXT_ 32
#define VID_ 1024
#define SS_  (S_*S_)          // 1115136
#define NQT_ 66               // q-tiles of 16 rows

#define LOG2_10000f 13.28771237954945f
#define LOG2_GAMMAf (-0.15200309344504995f)   // log2(0.9)
#define RSQRT_DKf   0.17677669529663687f      // 1/sqrt(32)
#define TWO_PIf     6.283185307179586f

typedef __attribute__((ext_vector_type(8))) short bf16x8;
typedef __attribute__((ext_vector_type(4))) float f32x4;

__device__ __forceinline__ short f2bf(float f){
    unsigned u = __float_as_uint(f);
    unsigned r = u + 0x7FFFu + ((u >> 16) & 1u);   // RNE
    return (short)(r >> 16);
}
__device__ __forceinline__ float bf2f(unsigned short s){
    return __uint_as_float(((unsigned)s) << 16);
}

// ---------------- mask (bf16) + loss partials ----------------
__global__ __launch_bounds__(256) void k_mask(const float* __restrict__ lvr,
                       const int* __restrict__ row_idx, const int* __restrict__ col_idx,
                       short* __restrict__ maskb, float* __restrict__ partials)
{
    int idx = blockIdx.x*256 + threadIdx.x;
    unsigned ui = (unsigned)idx;
    int i = ui / S_;
    int j = (int)(ui - (unsigned)i*S_);
    float vr, lm;
    if (i == j) { vr = 0.f; lm = 1.f; }
    else {
        float t = lvr[(size_t)row_idx[idx]*VID_ + col_idx[idx]];
        float sg = 1.f/(1.f + expf(-t));
        vr = sg; lm = sg;
    }
    float dmat = (i >= j) ? exp2f((float)(i-j)*LOG2_GAMMAf) : 0.f;
    maskb[idx] = f2bf(dmat * lm);
    float s = vr;
    #pragma unroll
    for (int m=1; m<64; m<<=1) s += __shfl_xor(s, m, 64);
    __shared__ float ws4[4];
    if ((threadIdx.x & 63) == 0) ws4[threadIdx.x>>6] = s;
    __syncthreads();
    if (threadIdx.x == 0) partials[blockIdx.x] = ws4[0]+ws4[1]+ws4[2]+ws4[3];
}

__global__ __launch_bounds__(256) void k_loss(const float* __restrict__ partials,
                                              float* __restrict__ out_loss)
{
    float s = 0.f;
    for (int i = threadIdx.x; i < SS_/256; i += 256) s += partials[i];
    #pragma unroll
    for (int m=1; m<64; m<<=1) s += __shfl_xor(s, m, 64);
    __shared__ float ws4[4];
    if ((threadIdx.x & 63) == 0) ws4[threadIdx.x>>6] = s;
    __syncthreads();
    if (threadIdx.x == 0) out_loss[0] = (ws4[0]+ws4[1]+ws4[2]+ws4[3]) * (1.f/(float)SS_);
}

// ---------------- W_out transpose ----------------
__global__ __launch_bounds__(256) void k_wot(const float* __restrict__ Wout,
                                             float* __restrict__ WoT)
{
    int t = blockIdx.x*256 + threadIdx.x;
    WoT[t] = Wout[(t & 255)*DM_ + (t >> 8)];
}

// ---------------- QKV projection -> bf16 Q,K row-major + bf16 V^T ----------------
__global__ __launch_bounds__(256) void k_qkv(const float* __restrict__ src,
    const float* __restrict__ Wq, const float* __restrict__ Wk, const float* __restrict__ Wv,
    short* __restrict__ Qb, short* __restrict__ Kb, short* __restrict__ VT, int is_txt)
{
    __shared__ float xt[3][DM_][20];
    __shared__ __align__(16) short vt16[DM_][24];
    int tid = threadIdx.x;
    int r0 = blockIdx.x * 16;
    int b, srow0;
    if (is_txt) { b = r0 >> 5;  srow0 = r0 & 31; }
    else        { b = r0 >> 10; srow0 = TXT_ + (r0 & 1023); }

    for (int it = 0; it < 8; ++it) {
        int task = it*256 + tid;
        int k  = task >> 4;
        int rr = task & 15;
        int srow = srow0 + rr;
        float2 x01 = ((const float2*)(src + ((size_t)b*S_ + srow)*DM_))[k];
        if (is_txt) {
            float xe  = (float)(srow + 1) * (TWO_PIf/(32.f + 1e-6f));
            float arg = xe * exp2f(-((float)k*(1.f/128.f))*LOG2_10000f);
            float p0 = sinf(arg), p1 = cosf(arg);
            xt[0][2*k  ][rr] = x01.x + p0;
            xt[0][2*k+1][rr] = x01.y + p1;
            xt[1][2*k  ][rr] = x01.x + p0;
            xt[1][2*k+1][rr] = x01.y + p1;
        } else {
            int l = srow - TXT_;
            float inv_freq = exp2f(-((float)k*(1.f/128.f))*LOG2_10000f);
            float arg = (float)l * inv_freq;
            float sn = sinf(arg), cs = cosf(arg);
            float base = ((float)(2*k) + 102.4f) * (1.f/358.4f);
            float scale = exp2f(((float)l*(1.f/512.f)) * log2f(base));
            float rsc = 1.f/scale;
            float y0 = x01.x*cs - x01.y*sn;
            float y1 = x01.y*cs + x01.x*sn;
            xt[0][2*k  ][rr] = y0*scale;  xt[0][2*k+1][rr] = y1*scale;
            xt[1][2*k  ][rr] = y0*rsc;    xt[1][2*k+1][rr] = y1*rsc;
        }
        xt[2][2*k  ][rr] = x01.x;
        xt[2][2*k+1][rr] = x01.y;
    }
    __syncthreads();

    int og = tid & 63, rg = tid >> 6;
    float aq[4][4], ak[4][4], av[4][4];
    #pragma unroll
    for (int c=0;c<4;c++)
      #pragma unroll
      for (int jr=0;jr<4;jr++){ aq[c][jr]=0.f; ak[c][jr]=0.f; av[c][jr]=0.f; }

    for (int e = 0; e < DM_; ++e) {
        float4 xq = *(const float4*)&xt[0][e][rg*4];
        float4 xk = *(const float4*)&xt[1][e][rg*4];
        float4 xv = *(const float4*)&xt[2][e][rg*4];
        float4 wq = *(const float4*)&Wq[e*DM_ + og*4];
        float4 wk = *(const float4*)&Wk[e*DM_ + og*4];
        float4 wv = *(const float4*)&Wv[e*DM_ + og*4];
        float xqa[4] = {xq.x,xq.y,xq.z,xq.w};
        float xka[4] = {xk.x,xk.y,xk.z,xk.w};
        float xva[4] = {xv.x,xv.y,xv.z,xv.w};
        #pragma unroll
        for (int jr=0;jr<4;jr++){
            aq[0][jr] = fmaf(xqa[jr], wq.x, aq[0][jr]);
            aq[1][jr] = fmaf(xqa[jr], wq.y, aq[1][jr]);
            aq[2][jr] = fmaf(xqa[jr], wq.z, aq[2][jr]);
            aq[3][jr] = fmaf(xqa[jr], wq.w, aq[3][jr]);
            ak[0][jr] = fmaf(xka[jr], wk.x, ak[0][jr]);
            ak[1][jr] = fmaf(xka[jr], wk.y, ak[1][jr]);
            ak[2][jr] = fmaf(xka[jr], wk.z, ak[2][jr]);
            ak[3][jr] = fmaf(xka[jr], wk.w, ak[3][jr]);
            av[0][jr] = fmaf(xva[jr], wv.x, av[0][jr]);
            av[1][jr] = fmaf(xva[jr], wv.y, av[1][jr]);
            av[2][jr] = fmaf(xva[jr], wv.z, av[2][jr]);
            av[3][jr] = fmaf(xva[jr], wv.w, av[3][jr]);
        }
    }
    int head = og >> 3;
    int dbase = (og & 7) * 4;
    #pragma unroll
    for (int jr=0;jr<4;jr++){
        int srow = srow0 + rg*4 + jr;
        size_t off = ((size_t)(b*H_ + head)*S_ + srow)*DK_ + dbase;
        short4 q4; q4.x=f2bf(aq[0][jr]*RSQRT_DKf); q4.y=f2bf(aq[1][jr]*RSQRT_DKf);
                   q4.z=f2bf(aq[2][jr]*RSQRT_DKf); q4.w=f2bf(aq[3][jr]*RSQRT_DKf);
        short4 k4; k4.x=f2bf(ak[0][jr]); k4.y=f2bf(ak[1][jr]);
                   k4.z=f2bf(ak[2][jr]); k4.w=f2bf(ak[3][jr]);
        *(short4*)&Qb[off] = q4;
        *(short4*)&Kb[off] = k4;
        #pragma unroll
        for (int c=0;c<4;c++) vt16[og*4+c][rg*4+jr] = f2bf(av[c][jr]);
    }
    __syncthreads();
    {
        bf16x8 v0 = *(const bf16x8*)&vt16[tid][0];
        bf16x8 v1 = *(const bf16x8*)&vt16[tid][8];
        size_t vtoff = ((size_t)(b*H_ + (tid>>5))*DK_ + (tid&31))*SP_ + srow0;
        *(bf16x8*)&VT[vtoff]     = v0;
        *(bf16x8*)&VT[vtoff + 8] = v1;
    }
}

// ---------------- kernel A: denominators + ctx ----------------
// mask held in registers for the whole block (t-invariant across heads).
// Phase 1: 2-stage K-frag pipeline, branch-free t=0..15, peeled t=16 tail.
// PV: dual accumulator chains. 2 barriers/head (rs double-buffered by parity).
__global__ __launch_bounds__(256, 4) void k_ctx(const short* __restrict__ Qb,
    const short* __restrict__ Kb, const short* __restrict__ VT,
    const short* __restrict__ maskb, float* __restrict__ ctx, float* __restrict__ denomG)
{
    __shared__ __align__(16) short P[16][SP_];    // 34.0 KB
    __shared__ float rs[2][4][16];
    __shared__ float pv_red[16][36];

    int tid  = threadIdx.x;
    int lane = tid & 63;
    int w    = tid >> 6;
    int b    = blockIdx.x & 15;   // qt-major: 16 adjacent blocks share mask rows
    int qt   = blockIdx.x >> 4;
    int q0   = qt * 16;

    int lr = lane & 15;
    int lg = lane >> 4;
    int dh = w & 1;
    int kh = w >> 1;
    int swq = (lr & 7) << 3;

    // ---- mask registers: rows fixed (lr), cols k0+lg*4, t=0..16 ----
    ushort4 mreg[16];
    const short* mrow = maskb + (size_t)(q0+lr)*S_ + w*16 + lg*4;
    #pragma unroll
    for (int t = 0; t < 16; ++t) mreg[t] = *(const ushort4*)(mrow + t*64);
    ushort4 mtail = make_ushort4(0,0,0,0);
    if (w < 2) mtail = *(const ushort4*)(mrow + 16*64);

    for (int h = 0; h < H_; ++h) {
        const short* Qp = Qb + ((size_t)(b*H_+h)*S_ + q0)*DK_;
        const short* Kp = Kb + (size_t)(b*H_+h)*S_*DK_ + (size_t)(w*16+lr)*DK_ + lg*8;
        bf16x8 qfrag = *(const bf16x8*)(Qp + lr*DK_ + lg*8);

        // ---- phase 1: scores + exp -> P (K-frag pipelined 2-deep) ----
        float rssum = 0.f;
        bf16x8 kf = *(const bf16x8*)Kp;
        #pragma unroll
        for (int t = 0; t < 16; ++t) {
            bf16x8 kcur = kf;
            if (t < 15)      kf = *(const bf16x8*)(Kp + (size_t)(t+1)*64*DK_);
            else if (w < 2)  kf = *(const bf16x8*)(Kp + (size_t)16*64*DK_);
            f32x4 acc = {0.f,0.f,0.f,0.f};
            acc = __builtin_amdgcn_mfma_f32_16x16x32_bf16(kcur, qfrag, acc, 0, 0, 0);
            float e0 = __expf(acc[0]*bf2f(mreg[t].x));
            float e1 = __expf(acc[1]*bf2f(mreg[t].y));
            float e2 = __expf(acc[2]*bf2f(mreg[t].z));
            float e3 = __expf(acc[3]*bf2f(mreg[t].w));
            rssum += (e0+e1) + (e2+e3);
            short4 s4; s4.x=f2bf(e0); s4.y=f2bf(e1); s4.z=f2bf(e2); s4.w=f2bf(e3);
            *(short4*)&P[lr][(t*64 + w*16 + lg*4) ^ swq] = s4;
        }
        {   // tail t=16 (only w<2 has real columns; others zero-pad)
            short4 s4; s4.x=0; s4.y=0; s4.z=0; s4.w=0;
            if (w < 2) {
                f32x4 acc = {0.f,0.f,0.f,0.f};
                acc = __builtin_amdgcn_mfma_f32_16x16x32_bf16(kf, qfrag, acc, 0, 0, 0);
                float e0 = __expf(acc[0]*bf2f(mtail.x));
                float e1 = __expf(acc[1]*bf2f(mtail.y));
                float e2 = __expf(acc[2]*bf2f(mtail.z));
                float e3 = __expf(acc[3]*bf2f(mtail.w));
                rssum += (e0+e1) + (e2+e3);
                s4.x=f2bf(e0); s4.y=f2bf(e1); s4.z=f2bf(e2); s4.w=f2bf(e3);
            }
            *(short4*)&P[lr][(1024 + w*16 + lg*4) ^ swq] = s4;
        }
        // ---- row sums ----
        rssum += __shfl_xor(rssum, 16, 64);
        rssum += __shfl_xor(rssum, 32, 64);
        if (lane < 16) rs[h&1][w][lr] = rssum;
        __syncthreads();   // P + rs ready
        if (tid < 16) {
            float rd = 1.f/(rs[h&1][0][tid]+rs[h&1][1][tid]+rs[h&1][2][tid]+rs[h&1][3][tid]);
            denomG[(size_t)(b*H_+h)*S_ + q0 + tid] = rd;
        }

        // ---- PV: dual accumulator chains over this wave's 17 k-tiles ----
        const short* Vp = VT + ((size_t)(b*H_+h)*DK_ + dh*16 + lr)*SP_ + lg*8;
        int kbase = kh * 17 * 32;
        f32x4 pv0 = {0.f,0.f,0.f,0.f}, pv1 = {0.f,0.f,0.f,0.f};
        #pragma unroll
        for (int u = 0; u < 8; ++u) {
            int kbA = kbase + (2*u  )*32;
            int kbB = kbase + (2*u+1)*32;
            bf16x8 pfA = *(const bf16x8*)&P[lr][(kbA + lg*8) ^ swq];
            bf16x8 vfA = *(const bf16x8*)(Vp + kbA);
            bf16x8 pfB = *(const bf16x8*)&P[lr][(kbB + lg*8) ^ swq];
            bf16x8 vfB = *(const bf16x8*)(Vp + kbB);
            pv0 = __builtin_amdgcn_mfma_f32_16x16x32_bf16(pfA, vfA, pv0, 0, 0, 0);
            pv1 = __builtin_amdgcn_mfma_f32_16x16x32_bf16(pfB, vfB, pv1, 0, 0, 0);
        }
        {   // 17th tile
            int kb = kbase + 16*32;
            bf16x8 pf = *(const bf16x8*)&P[lr][(kb + lg*8) ^ swq];
            bf16x8 vf = *(const bf16x8*)(Vp + kb);
            pv0 = __builtin_amdgcn_mfma_f32_16x16x32_bf16(pf, vf, pv0, 0, 0, 0);
        }
        f32x4 pvacc;
        pvacc[0]=pv0[0]+pv1[0]; pvacc[1]=pv0[1]+pv1[1];
        pvacc[2]=pv0[2]+pv1[2]; pvacc[3]=pv0[3]+pv1[3];

        if (kh == 1) {
            #pragma unroll
            for (int r = 0; r < 4; ++r) pv_red[lg*4+r][dh*16+lr] = pvacc[r];
        }
        __syncthreads();
        if (kh == 0) {
            #pragma unroll
            for (int r = 0; r < 4; ++r) {
                int qq = lg*4 + r;
                float rd = 1.f/(rs[h&1][0][qq]+rs[h&1][1][qq]+rs[h&1][2][qq]+rs[h&1][3][qq]);
                float v = pvacc[r] + pv_red[qq][dh*16+lr];
                ctx[((size_t)b*S_ + q0+qq)*DM_ + h*DK_ + dh*16 + lr] = v * rd;
            }
        }
        // no loop-end barrier: next head writes P (no readers left) and rs[(h+1)&1]
    }
}

// ---------------- kernel B: att by score recompute, t-outer / h-inner ----------------
__global__ __launch_bounds__(256, 4) void k_att(const short* __restrict__ Qb,
    const short* __restrict__ Kb, const short* __restrict__ maskb,
    const float* __restrict__ denomG, float* __restrict__ att)
{
    __shared__ float rd_l[8][16];
    int tid  = threadIdx.x;
    int lane = tid & 63;
    int w    = tid >> 6;
    int b    = blockIdx.x & 15;
    int qt   = blockIdx.x >> 4;
    int q0   = qt * 16;

    if (tid < 128)
        rd_l[tid>>4][tid&15] = denomG[(size_t)(b*H_+(tid>>4))*S_ + q0 + (tid&15)] * 0.125f;
    __syncthreads();

    int lr = lane & 15;
    int lg = lane >> 4;

    // hoist Q fragments for all 8 heads (t-invariant)
    bf16x8 qf[8];
    #pragma unroll
    for (int h = 0; h < 8; ++h)
        qf[h] = *(const bf16x8*)(Qb + ((size_t)(b*H_+h)*S_ + q0+lr)*DK_ + lg*8);

    const size_t kstride = (size_t)S_*DK_;
    const short* Kbase = Kb + (size_t)b*H_*kstride + lg*8;

    int nt = (w < 2) ? 17 : 16;    // wave-uniform trip count; t=16 tail only for w<2
    for (int t = 0; t < nt; ++t) {
        int k0 = t*64 + w*16;
        float m0 = bf2f((unsigned short)maskb[(size_t)(q0+4*lg+0)*S_ + k0+lr]);
        float m1 = bf2f((unsigned short)maskb[(size_t)(q0+4*lg+1)*S_ + k0+lr]);
        float m2 = bf2f((unsigned short)maskb[(size_t)(q0+4*lg+2)*S_ + k0+lr]);
        float m3 = bf2f((unsigned short)maskb[(size_t)(q0+4*lg+3)*S_ + k0+lr]);
        f32x4 a = {0.f,0.f,0.f,0.f};
        #pragma unroll
        for (int h = 0; h < 8; ++h) {
            bf16x8 kfrag = *(const bf16x8*)(Kbase + (size_t)h*kstride + (size_t)(k0+lr)*DK_);
            f32x4 s = {0.f,0.f,0.f,0.f};
            s = __builtin_amdgcn_mfma_f32_16x16x32_bf16(qf[h], kfrag, s, 0, 0, 0);
            a[0] = fmaf(__expf(s[0]*m0), rd_l[h][4*lg+0], a[0]);
            a[1] = fmaf(__expf(s[1]*m1), rd_l[h][4*lg+1], a[1]);
            a[2] = fmaf(__expf(s[2]*m2), rd_l[h][4*lg+2], a[2]);
            a[3] = fmaf(__expf(s[3]*m3), rd_l[h][4*lg+3], a[3]);
        }
        att[((size_t)b*S_ + q0+4*lg+0)*S_ + k0+lr] = a[0];
        att[((size_t)b*S_ + q0+4*lg+1)*S_ + k0+lr] = a[1];
        att[((size_t)b*S_ + q0+4*lg+2)*S_ + k0+lr] = a[2];
        att[((size_t)b*S_ + q0+4*lg+3)*S_ + k0+lr] = a[3];
    }
}

// ---------------- out projection ----------------
__global__ __launch_bounds__(256) void k_outproj(const float* __restrict__ ctxp,
    const float* __restrict__ WoT, const float* __restrict__ bias, float* __restrict__ out)
{
    __shared__ float ct[DM_][20];
    int tid = threadIdx.x;
    int r0 = blockIdx.x * 16;
    for (int it = 0; it < 16; ++it) {
        int task = it*256 + tid;
        int col = task >> 4;
        int rr  = task & 15;
        ct[col][rr] = ctxp[(size_t)(r0+rr)*DM_ + col];
    }
    __syncthreads();
    int og = tid & 63, rg = tid >> 6;
    float acc[4][4];
    #pragma unroll
    for (int c=0;c<4;c++)
      #pragma unroll
      for (int jr=0;jr<4;jr++) acc[c][jr] = 0.f;
    for (int e = 0; e < DM_; ++e){
        float4 x4 = *(const float4*)&ct[e][rg*4];
        float4 w4 = *(const float4*)&WoT[e*DM_ + og*4];
        float xa[4] = {x4.x,x4.y,x4.z,x4.w};
        #pragma unroll
        for (int jr=0;jr<4;jr++){
            acc[0][jr] = fmaf(xa[jr], w4.x, acc[0][jr]);
            acc[1][jr] = fmaf(xa[jr], w4.y, acc[1][jr]);
            acc[2][jr] = fmaf(xa[jr], w4.z, acc[2][jr]);
            acc[3][jr] = fmaf(xa[jr], w4.w, acc[3][jr]);
        }
    }
    float4 b4 = *(const float4*)&bias[og*4];
    #pragma unroll
    for (int jr=0;jr<4;jr++){
        int r = r0 + rg*4 + jr;
        float4 o4 = make_float4(acc[0][jr]+b4.x, acc[1][jr]+b4.y,
                                acc[2][jr]+b4.z, acc[3][jr]+b4.w);
        *(float4*)&out[(size_t)r*DM_ + og*4] = o4;
    }
}

extern "C" void kernel_launch(void* const* d_in, const int* in_sizes, int n_in,
                              void* d_out, int out_size, void* d_ws, size_t ws_size,
                              hipStream_t stream)
{
    (void)in_sizes; (void)n_in; (void)out_size; (void)ws_size;
    const float* src  = (const float*)d_in[0];
    const float* Wtq  = (const float*)d_in[1];
    const float* Wtk  = (const float*)d_in[2];
    const float* Wtv  = (const float*)d_in[3];
    const float* Wvq  = (const float*)d_in[4];
    const float* Wvk  = (const float*)d_in[5];
    const float* Wvv  = (const float*)d_in[6];
    const float* lvr  = (const float*)d_in[7];
    const float* Wout = (const float*)d_in[8];
    const float* bout = (const float*)d_in[9];
    const int*   rid  = (const int*)d_in[10];
    const int*   cid  = (const int*)d_in[11];

    const size_t QKV_SH = (size_t)B_*H_*S_*DK_;    // shorts per Q/K buffer
    const size_t VT_SH  = (size_t)B_*H_*DK_*SP_;   // shorts for V^T

    float* ws       = (float*)d_ws;
    float* ctx      = ws;                           // B*S*DM
    float* WoT      = ctx + (size_t)B_*S_*DM_;      // 65536
    float* partials = WoT + DM_*DM_;                // 4356
    float* denomG   = partials + 4356;              // B*H*S = 135168
    short* maskb    = (short*)(denomG + (size_t)B_*H_*S_);
    short* Qb       = maskb + SS_;
    short* Kb       = Qb + QKV_SH;
    short* VT       = Kb + QKV_SH;
    (void)VT_SH;

    float* out  = (float*)d_out;
    float* att  = out + (size_t)B_*S_*DM_;
    float* loss = att + (size_t)B_*S_*S_;

    k_mask<<<SS_/256, 256, 0, stream>>>(lvr, rid, cid, maskb, partials);
    k_wot<<<DM_*DM_/256, 256, 0, stream>>>(Wout, WoT);
    k_qkv<<<(B_*TXT_)/16, 256, 0, stream>>>(src, Wtq, Wtk, Wtv, Qb, Kb, VT, 1);
    k_qkv<<<(B_*VID_)/16, 256, 0, stream>>>(src, Wvq, Wvk, Wvv, Qb, Kb, VT, 0);
    k_ctx<<<B_*NQT_, 256, 0, stream>>>(Qb, Kb, VT, maskb, ctx, denomG);
    k_att<<<B_*NQT_, 256, 0, stream>>>(Qb, Kb, maskb, denomG, att);
    k_outproj<<<(B_*S_)/16, 256, 0, stream>>>(ctx, WoT, bout, out);
    k_loss<<<1, 256, 0, stream>>>(partials, loss);
}

// Round 6
// 426.438 us; speedup vs baseline: 1.4913x; 1.4913x over previous
//
#include <hip/hip_runtime.h>
#include <math.h>

#define B_   16
#define S_   1056
#define SP_  1088             // k padded to 34*32
#define DM_  256
#define H_   8
#define DK_  32
#define TXT_ 32
#define VID_ 1024
#define SS_  (S_*S_)          // 1115136
#define NQT_ 66               // q-tiles of 16 rows

#define LOG2_10000f 13.28771237954945f
#define LOG2_GAMMAf (-0.15200309344504995f)   // log2(0.9)
#define RSQRT_DKf   0.17677669529663687f      // 1/sqrt(32)
#define TWO_PIf     6.283185307179586f

typedef __attribute__((ext_vector_type(8))) short bf16x8;
typedef __attribute__((ext_vector_type(4))) float f32x4;

__device__ __forceinline__ short f2bf(float f){
    unsigned u = __float_as_uint(f);
    unsigned r = u + 0x7FFFu + ((u >> 16) & 1u);   // RNE
    return (short)(r >> 16);
}
__device__ __forceinline__ float bf2f(unsigned short s){
    return __uint_as_float(((unsigned)s) << 16);
}

// ---------------- mask (bf16) + loss partials ----------------
__global__ __launch_bounds__(256) void k_mask(const float* __restrict__ lvr,
                       const int* __restrict__ row_idx, const int* __restrict__ col_idx,
                       short* __restrict__ maskb, float* __restrict__ partials)
{
    int idx = blockIdx.x*256 + threadIdx.x;
    unsigned ui = (unsigned)idx;
    int i = ui / S_;
    int j = (int)(ui - (unsigned)i*S_);
    float vr, lm;
    if (i == j) { vr = 0.f; lm = 1.f; }
    else {
        float t = lvr[(size_t)row_idx[idx]*VID_ + col_idx[idx]];
        float sg = 1.f/(1.f + expf(-t));
        vr = sg; lm = sg;
    }
    float dmat = (i >= j) ? exp2f((float)(i-j)*LOG2_GAMMAf) : 0.f;
    maskb[idx] = f2bf(dmat * lm);
    float s = vr;
    #pragma unroll
    for (int m=1; m<64; m<<=1) s += __shfl_xor(s, m, 64);
    __shared__ float ws4[4];
    if ((threadIdx.x & 63) == 0) ws4[threadIdx.x>>6] = s;
    __syncthreads();
    if (threadIdx.x == 0) partials[blockIdx.x] = ws4[0]+ws4[1]+ws4[2]+ws4[3];
}

__global__ __launch_bounds__(256) void k_loss(const float* __restrict__ partials,
                                              float* __restrict__ out_loss)
{
    float s = 0.f;
    for (int i = threadIdx.x; i < SS_/256; i += 256) s += partials[i];
    #pragma unroll
    for (int m=1; m<64; m<<=1) s += __shfl_xor(s, m, 64);
    __shared__ float ws4[4];
    if ((threadIdx.x & 63) == 0) ws4[threadIdx.x>>6] = s;
    __syncthreads();
    if (threadIdx.x == 0) out_loss[0] = (ws4[0]+ws4[1]+ws4[2]+ws4[3]) * (1.f/(float)SS_);
}

// ---------------- W_out transpose ----------------
__global__ __launch_bounds__(256) void k_wot(const float* __restrict__ Wout,
                                             float* __restrict__ WoT)
{
    int t = blockIdx.x*256 + threadIdx.x;
    WoT[t] = Wout[(t & 255)*DM_ + (t >> 8)];
}

// ---------------- QKV projection -> bf16 Q,K row-major + bf16 V^T ----------------
__global__ __launch_bounds__(256) void k_qkv(const float* __restrict__ src,
    const float* __restrict__ Wq, const float* __restrict__ Wk, const float* __restrict__ Wv,
    short* __restrict__ Qb, short* __restrict__ Kb, short* __restrict__ VT, int is_txt)
{
    __shared__ float xt[3][DM_][20];
    __shared__ __align__(16) short vt16[DM_][24];
    int tid = threadIdx.x;
    int r0 = blockIdx.x * 16;
    int b, srow0;
    if (is_txt) { b = r0 >> 5;  srow0 = r0 & 31; }
    else        { b = r0 >> 10; srow0 = TXT_ + (r0 & 1023); }

    for (int it = 0; it < 8; ++it) {
        int task = it*256 + tid;
        int k  = task >> 4;
        int rr = task & 15;
        int srow = srow0 + rr;
        float2 x01 = ((const float2*)(src + ((size_t)b*S_ + srow)*DM_))[k];
        if (is_txt) {
            float xe  = (float)(srow + 1) * (TWO_PIf/(32.f + 1e-6f));
            float arg = xe * exp2f(-((float)k*(1.f/128.f))*LOG2_10000f);
            float p0 = sinf(arg), p1 = cosf(arg);
            xt[0][2*k  ][rr] = x01.x + p0;
            xt[0][2*k+1][rr] = x01.y + p1;
            xt[1][2*k  ][rr] = x01.x + p0;
            xt[1][2*k+1][rr] = x01.y + p1;
        } else {
            int l = srow - TXT_;
            float inv_freq = exp2f(-((float)k*(1.f/128.f))*LOG2_10000f);
            float arg = (float)l * inv_freq;
            float sn = sinf(arg), cs = cosf(arg);
            float base = ((float)(2*k) + 102.4f) * (1.f/358.4f);
            float scale = exp2f(((float)l*(1.f/512.f)) * log2f(base));
            float rsc = 1.f/scale;
            float y0 = x01.x*cs - x01.y*sn;
            float y1 = x01.y*cs + x01.x*sn;
            xt[0][2*k  ][rr] = y0*scale;  xt[0][2*k+1][rr] = y1*scale;
            xt[1][2*k  ][rr] = y0*rsc;    xt[1][2*k+1][rr] = y1*rsc;
        }
        xt[2][2*k  ][rr] = x01.x;
        xt[2][2*k+1][rr] = x01.y;
    }
    __syncthreads();

    int og = tid & 63, rg = tid >> 6;
    float aq[4][4], ak[4][4], av[4][4];
    #pragma unroll
    for (int c=0;c<4;c++)
      #pragma unroll
      for (int jr=0;jr<4;jr++){ aq[c][jr]=0.f; ak[c][jr]=0.f; av[c][jr]=0.f; }

    for (int e = 0; e < DM_; ++e) {
        float4 xq = *(const float4*)&xt[0][e][rg*4];
        float4 xk = *(const float4*)&xt[1][e][rg*4];
        float4 xv = *(const float4*)&xt[2][e][rg*4];
        float4 wq = *(const float4*)&Wq[e*DM_ + og*4];
        float4 wk = *(const float4*)&Wk[e*DM_ + og*4];
        float4 wv = *(const float4*)&Wv[e*DM_ + og*4];
        float xqa[4] = {xq.x,xq.y,xq.z,xq.w};
        float xka[4] = {xk.x,xk.y,xk.z,xk.w};
        float xva[4] = {xv.x,xv.y,xv.z,xv.w};
        #pragma unroll
        for (int jr=0;jr<4;jr++){
            aq[0][jr] = fmaf(xqa[jr], wq.x, aq[0][jr]);
            aq[1][jr] = fmaf(xqa[jr], wq.y, aq[1][jr]);
            aq[2][jr] = fmaf(xqa[jr], wq.z, aq[2][jr]);
            aq[3][jr] = fmaf(xqa[jr], wq.w, aq[3][jr]);
            ak[0][jr] = fmaf(xka[jr], wk.x, ak[0][jr]);
            ak[1][jr] = fmaf(xka[jr], wk.y, ak[1][jr]);
            ak[2][jr] = fmaf(xka[jr], wk.z, ak[2][jr]);
            ak[3][jr] = fmaf(xka[jr], wk.w, ak[3][jr]);
            av[0][jr] = fmaf(xva[jr], wv.x, av[0][jr]);
            av[1][jr] = fmaf(xva[jr], wv.y, av[1][jr]);
            av[2][jr] = fmaf(xva[jr], wv.z, av[2][jr]);
            av[3][jr] = fmaf(xva[jr], wv.w, av[3][jr]);
        }
    }
    int head = og >> 3;
    int dbase = (og & 7) * 4;
    #pragma unroll
    for (int jr=0;jr<4;jr++){
        int srow = srow0 + rg*4 + jr;
        size_t off = ((size_t)(b*H_ + head)*S_ + srow)*DK_ + dbase;
        short4 q4; q4.x=f2bf(aq[0][jr]*RSQRT_DKf); q4.y=f2bf(aq[1][jr]*RSQRT_DKf);
                   q4.z=f2bf(aq[2][jr]*RSQRT_DKf); q4.w=f2bf(aq[3][jr]*RSQRT_DKf);
        short4 k4; k4.x=f2bf(ak[0][jr]); k4.y=f2bf(ak[1][jr]);
                   k4.z=f2bf(ak[2][jr]); k4.w=f2bf(ak[3][jr]);
        *(short4*)&Qb[off] = q4;
        *(short4*)&Kb[off] = k4;
        #pragma unroll
        for (int c=0;c<4;c++) vt16[og*4+c][rg*4+jr] = f2bf(av[c][jr]);
    }
    __syncthreads();
    {
        bf16x8 v0 = *(const bf16x8*)&vt16[tid][0];
        bf16x8 v1 = *(const bf16x8*)&vt16[tid][8];
        size_t vtoff = ((size_t)(b*H_ + (tid>>5))*DK_ + (tid&31))*SP_ + srow0;
        *(bf16x8*)&VT[vtoff]     = v0;
        *(bf16x8*)&VT[vtoff + 8] = v1;
    }
}

// ---------------- kernel A: denominators + ctx ----------------
// launch_bounds (256,2): VGPR cap 256 so mask regs + 4-deep K pipeline fit (R5 spilled at 64).
// Phase 1: explicit 4-deep K-fragment batches (two alternating reg arrays, all
// indices compile-time). 2 barriers/head; rs double-buffered by head parity.
#define PH1_STEP(CUR, NXT, TB)                                                          \
    {                                                                                   \
        _Pragma("unroll")                                                               \
        for (int i = 0; i < 4; ++i) {                                                   \
            int tn = (TB) + 4 + i;                                                      \
            if (tn < 16)                                                                \
                NXT[i] = *(const bf16x8*)(Kp + (size_t)tn*64*DK_);                      \
            else if (tn == 16 && w < 2)                                                 \
                NXT[i] = *(const bf16x8*)(Kp + (size_t)16*64*DK_);                      \
        }                                                                               \
        _Pragma("unroll")                                                               \
        for (int i = 0; i < 4; ++i) {                                                   \
            const int t = (TB) + i;                                                     \
            f32x4 acc = {0.f,0.f,0.f,0.f};                                              \
            acc = __builtin_amdgcn_mfma_f32_16x16x32_bf16(CUR[i], qfrag, acc, 0, 0, 0); \
            float e0 = __expf(acc[0]*bf2f(mreg[t].x));                                  \
            float e1 = __expf(acc[1]*bf2f(mreg[t].y));                                  \
            float e2 = __expf(acc[2]*bf2f(mreg[t].z));                                  \
            float e3 = __expf(acc[3]*bf2f(mreg[t].w));                                  \
            rssum += (e0+e1) + (e2+e3);                                                 \
            short4 s4; s4.x=f2bf(e0); s4.y=f2bf(e1); s4.z=f2bf(e2); s4.w=f2bf(e3);      \
            *(short4*)&P[lr][(t*64 + w*16 + lg*4) ^ swq] = s4;                          \
        }                                                                               \
    }

__global__ __launch_bounds__(256, 2) void k_ctx(const short* __restrict__ Qb,
    const short* __restrict__ Kb, const short* __restrict__ VT,
    const short* __restrict__ maskb, float* __restrict__ ctx, float* __restrict__ denomG)
{
    __shared__ __align__(16) short P[16][SP_];    // 34.0 KB
    __shared__ float rs[2][4][16];
    __shared__ float pv_red[16][36];

    int tid  = threadIdx.x;
    int lane = tid & 63;
    int w    = tid >> 6;
    int b    = blockIdx.x & 15;   // qt-major: blocks sharing b land on the same XCD (stride 16 ≡ 0 mod 8)
    int qt   = blockIdx.x >> 4;
    int q0   = qt * 16;

    int lr = lane & 15;
    int lg = lane >> 4;
    int dh = w & 1;
    int kh = w >> 1;
    int swq = (lr & 7) << 3;

    // ---- mask registers: rows fixed (lr), cols k0+lg*4, t=0..16 ----
    ushort4 mreg[16];
    const short* mrow = maskb + (size_t)(q0+lr)*S_ + w*16 + lg*4;
    #pragma unroll
    for (int t = 0; t < 16; ++t) mreg[t] = *(const ushort4*)(mrow + t*64);
    ushort4 mtail = make_ushort4(0,0,0,0);
    if (w < 2) mtail = *(const ushort4*)(mrow + 16*64);

    for (int h = 0; h < H_; ++h) {
        const short* Qp = Qb + ((size_t)(b*H_+h)*S_ + q0)*DK_;
        const short* Kp = Kb + (size_t)(b*H_+h)*S_*DK_ + (size_t)(w*16+lr)*DK_ + lg*8;
        bf16x8 qfrag = *(const bf16x8*)(Qp + lr*DK_ + lg*8);

        // ---- phase 1: 4-deep pipelined scores + exp -> P ----
        float rssum = 0.f;
        bf16x8 kfa[4], kfb[4];
        #pragma unroll
        for (int i = 0; i < 4; ++i) kfa[i] = *(const bf16x8*)(Kp + (size_t)i*64*DK_);
        PH1_STEP(kfa, kfb, 0)
        PH1_STEP(kfb, kfa, 4)
        PH1_STEP(kfa, kfb, 8)
        PH1_STEP(kfb, kfa, 12)     // loads L(16) into kfa[0] for w<2
        {   // tail t=16 (only w<2 has real columns; others zero-pad)
            short4 s4; s4.x=0; s4.y=0; s4.z=0; s4.w=0;
            if (w < 2) {
                f32x4 acc = {0.f,0.f,0.f,0.f};
                acc = __builtin_amdgcn_mfma_f32_16x16x32_bf16(kfa[0], qfrag, acc, 0, 0, 0);
                float e0 = __expf(acc[0]*bf2f(mtail.x));
                float e1 = __expf(acc[1]*bf2f(mtail.y));
                float e2 = __expf(acc[2]*bf2f(mtail.z));
                float e3 = __expf(acc[3]*bf2f(mtail.w));
                rssum += (e0+e1) + (e2+e3);
                s4.x=f2bf(e0); s4.y=f2bf(e1); s4.z=f2bf(e2); s4.w=f2bf(e3);
            }
            *(short4*)&P[lr][(1024 + w*16 + lg*4) ^ swq] = s4;
        }
        // ---- row sums ----
        rssum += __shfl_xor(rssum, 16, 64);
        rssum += __shfl_xor(rssum, 32, 64);
        if (lane < 16) rs[h&1][w][lr] = rssum;
        __syncthreads();   // P + rs ready
        if (tid < 16) {
            float rd = 1.f/(rs[h&1][0][tid]+rs[h&1][1][tid]+rs[h&1][2][tid]+rs[h&1][3][tid]);
            denomG[(size_t)(b*H_+h)*S_ + q0 + tid] = rd;
        }

        // ---- PV: dual accumulator chains over this wave's 17 k-tiles ----
        const short* Vp = VT + ((size_t)(b*H_+h)*DK_ + dh*16 + lr)*SP_ + lg*8;
        int kbase = kh * 17 * 32;
        f32x4 pv0 = {0.f,0.f,0.f,0.f}, pv1 = {0.f,0.f,0.f,0.f};
        #pragma unroll
        for (int u = 0; u < 8; ++u) {
            int kbA = kbase + (2*u  )*32;
            int kbB = kbase + (2*u+1)*32;
            bf16x8 pfA = *(const bf16x8*)&P[lr][(kbA + lg*8) ^ swq];
            bf16x8 vfA = *(const bf16x8*)(Vp + kbA);
            bf16x8 pfB = *(const bf16x8*)&P[lr][(kbB + lg*8) ^ swq];
            bf16x8 vfB = *(const bf16x8*)(Vp + kbB);
            pv0 = __builtin_amdgcn_mfma_f32_16x16x32_bf16(pfA, vfA, pv0, 0, 0, 0);
            pv1 = __builtin_amdgcn_mfma_f32_16x16x32_bf16(pfB, vfB, pv1, 0, 0, 0);
        }
        {   // 17th tile
            int kb = kbase + 16*32;
            bf16x8 pf = *(const bf16x8*)&P[lr][(kb + lg*8) ^ swq];
            bf16x8 vf = *(const bf16x8*)(Vp + kb);
            pv0 = __builtin_amdgcn_mfma_f32_16x16x32_bf16(pf, vf, pv0, 0, 0, 0);
        }
        f32x4 pvacc;
        pvacc[0]=pv0[0]+pv1[0]; pvacc[1]=pv0[1]+pv1[1];
        pvacc[2]=pv0[2]+pv1[2]; pvacc[3]=pv0[3]+pv1[3];

        if (kh == 1) {
            #pragma unroll
            for (int r = 0; r < 4; ++r) pv_red[lg*4+r][dh*16+lr] = pvacc[r];
        }
        __syncthreads();
        if (kh == 0) {
            #pragma unroll
            for (int r = 0; r < 4; ++r) {
                int qq = lg*4 + r;
                float rd = 1.f/(rs[h&1][0][qq]+rs[h&1][1][qq]+rs[h&1][2][qq]+rs[h&1][3][qq]);
                float v = pvacc[r] + pv_red[qq][dh*16+lr];
                ctx[((size_t)b*S_ + q0+qq)*DM_ + h*DK_ + dh*16 + lr] = v * rd;
            }
        }
        // no loop-end barrier: next head's P writes are ordered after this head's
        // PV reads by the barrier above; rs is parity double-buffered.
    }
}

// ---------------- kernel B: att by score recompute, t-outer / h-inner ----------------
__global__ __launch_bounds__(256, 2) void k_att(const short* __restrict__ Qb,
    const short* __restrict__ Kb, const short* __restrict__ maskb,
    const float* __restrict__ denomG, float* __restrict__ att)
{
    __shared__ float rd_l[8][16];
    int tid  = threadIdx.x;
    int lane = tid & 63;
    int w    = tid >> 6;
    int b    = blockIdx.x & 15;
    int qt   = blockIdx.x >> 4;
    int q0   = qt * 16;

    if (tid < 128)
        rd_l[tid>>4][tid&15] = denomG[(size_t)(b*H_+(tid>>4))*S_ + q0 + (tid&15)] * 0.125f;
    __syncthreads();

    int lr = lane & 15;
    int lg = lane >> 4;

    // hoist Q fragments for all 8 heads (t-invariant)
    bf16x8 qf[8];
    #pragma unroll
    for (int h = 0; h < 8; ++h)
        qf[h] = *(const bf16x8*)(Qb + ((size_t)(b*H_+h)*S_ + q0+lr)*DK_ + lg*8);

    const size_t kstride = (size_t)S_*DK_;
    const short* Kbase = Kb + (size_t)b*H_*kstride + lg*8;

    int nt = (w < 2) ? 17 : 16;    // wave-uniform trip count; t=16 tail only for w<2
    for (int t = 0; t < nt; ++t) {
        int k0 = t*64 + w*16;
        float m0 = bf2f((unsigned short)maskb[(size_t)(q0+4*lg+0)*S_ + k0+lr]);
        float m1 = bf2f((unsigned short)maskb[(size_t)(q0+4*lg+1)*S_ + k0+lr]);
        float m2 = bf2f((unsigned short)maskb[(size_t)(q0+4*lg+2)*S_ + k0+lr]);
        float m3 = bf2f((unsigned short)maskb[(size_t)(q0+4*lg+3)*S_ + k0+lr]);
        f32x4 a = {0.f,0.f,0.f,0.f};
        #pragma unroll
        for (int h = 0; h < 8; ++h) {
            bf16x8 kfrag = *(const bf16x8*)(Kbase + (size_t)h*kstride + (size_t)(k0+lr)*DK_);
            f32x4 s = {0.f,0.f,0.f,0.f};
            s = __builtin_amdgcn_mfma_f32_16x16x32_bf16(qf[h], kfrag, s, 0, 0, 0);
            a[0] = fmaf(__expf(s[0]*m0), rd_l[h][4*lg+0], a[0]);
            a[1] = fmaf(__expf(s[1]*m1), rd_l[h][4*lg+1], a[1]);
            a[2] = fmaf(__expf(s[2]*m2), rd_l[h][4*lg+2], a[2]);
            a[3] = fmaf(__expf(s[3]*m3), rd_l[h][4*lg+3], a[3]);
        }
        att[((size_t)b*S_ + q0+4*lg+0)*S_ + k0+lr] = a[0];
        att[((size_t)b*S_ + q0+4*lg+1)*S_ + k0+lr] = a[1];
        att[((size_t)b*S_ + q0+4*lg+2)*S_ + k0+lr] = a[2];
        att[((size_t)b*S_ + q0+4*lg+3)*S_ + k0+lr] = a[3];
    }
}

// ---------------- out projection ----------------
__global__ __launch_bounds__(256) void k_outproj(const float* __restrict__ ctxp,
    const float* __restrict__ WoT, const float* __restrict__ bias, float* __restrict__ out)
{
    __shared__ float ct[DM_][20];
    int tid = threadIdx.x;
    int r0 = blockIdx.x * 16;
    for (int it = 0; it < 16; ++it) {
        int task = it*256 + tid;
        int col = task >> 4;
        int rr  = task & 15;
        ct[col][rr] = ctxp[(size_t)(r0+rr)*DM_ + col];
    }
    __syncthreads();
    int og = tid & 63, rg = tid >> 6;
    float acc[4][4];
    #pragma unroll
    for (int c=0;c<4;c++)
      #pragma unroll
      for (int jr=0;jr<4;jr++) acc[c][jr] = 0.f;
    for (int e = 0; e < DM_; ++e){
        float4 x4 = *(const float4*)&ct[e][rg*4];
        float4 w4 = *(const float4*)&WoT[e*DM_ + og*4];
        float xa[4] = {x4.x,x4.y,x4.z,x4.w};
        #pragma unroll
        for (int jr=0;jr<4;jr++){
            acc[0][jr] = fmaf(xa[jr], w4.x, acc[0][jr]);
            acc[1][jr] = fmaf(xa[jr], w4.y, acc[1][jr]);
            acc[2][jr] = fmaf(xa[jr], w4.z, acc[2][jr]);
            acc[3][jr] = fmaf(xa[jr], w4.w, acc[3][jr]);
        }
    }
    float4 b4 = *(const float4*)&bias[og*4];
    #pragma unroll
    for (int jr=0;jr<4;jr++){
        int r = r0 + rg*4 + jr;
        float4 o4 = make_float4(acc[0][jr]+b4.x, acc[1][jr]+b4.y,
                                acc[2][jr]+b4.z, acc[3][jr]+b4.w);
        *(float4*)&out[(size_t)r*DM_ + og*4] = o4;
    }
}

extern "C" void kernel_launch(void* const* d_in, const int* in_sizes, int n_in,
                              void* d_out, int out_size, void* d_ws, size_t ws_size,
                              hipStream_t stream)
{
    (void)in_sizes; (void)n_in; (void)out_size; (void)ws_size;
    const float* src  = (const float*)d_in[0];
    const float* Wtq  = (const float*)d_in[1];
    const float* Wtk  = (const float*)d_in[2];
    const float* Wtv  = (const float*)d_in[3];
    const float* Wvq  = (const float*)d_in[4];
    const float* Wvk  = (const float*)d_in[5];
    const float* Wvv  = (const float*)d_in[6];
    const float* lvr  = (const float*)d_in[7];
    const float* Wout = (const float*)d_in[8];
    const float* bout = (const float*)d_in[9];
    const int*   rid  = (const int*)d_in[10];
    const int*   cid  = (const int*)d_in[11];

    const size_t QKV_SH = (size_t)B_*H_*S_*DK_;    // shorts per Q/K buffer

    float* ws       = (float*)d_ws;
    float* ctx      = ws;                           // B*S*DM
    float* WoT      = ctx + (size_t)B_*S_*DM_;      // 65536
    float* partials = WoT + DM_*DM_;                // 4356
    float* denomG   = partials + 4356;              // B*H*S = 135168
    short* maskb    = (short*)(denomG + (size_t)B_*H_*S_);
    short* Qb       = maskb + SS_;
    short* Kb       = Qb + QKV_SH;
    short* VT       = Kb + QKV_SH;

    float* out  = (float*)d_out;
    float* att  = out + (size_t)B_*S_*DM_;
    float* loss = att + (size_t)B_*S_*S_;

    k_mask<<<SS_/256, 256, 0, stream>>>(lvr, rid, cid, maskb, partials);
    k_wot<<<DM_*DM_/256, 256, 0, stream>>>(Wout, WoT);
    k_qkv<<<(B_*TXT_)/16, 256, 0, stream>>>(src, Wtq, Wtk, Wtv, Qb, Kb, VT, 1);
    k_qkv<<<(B_*VID_)/16, 256, 0, stream>>>(src, Wvq, Wvk, Wvv, Qb, Kb, VT, 0);
    k_ctx<<<B_*NQT_, 256, 0, stream>>>(Qb, Kb, VT, maskb, ctx, denomG);
    k_att<<<B_*NQT_, 256, 0, stream>>>(Qb, Kb, maskb, denomG, att);
    k_outproj<<<(B_*S_)/16, 256, 0, stream>>>(ctx, WoT, bout, out);
    k_loss<<<1, 256, 0, stream>>>(partials, loss);
}

// Round 7
// 309.026 us; speedup vs baseline: 2.0578x; 1.3799x over previous
//
#include <hip/hip_runtime.h>
#include <math.h>

#define B_   16
#define S_   1056
#define SP_  1088             // k padded to 34*32
#define DM_  256
#define H_   8
#define DK_  32
#define TXT_ 32
#define VID_ 1024
#define SS_  (S_*S_)          // 1115136
#define NQT_ 66               // q-tiles of 16 rows

#define LOG2_10000f 13.28771237954945f
#define LOG2_GAMMAf (-0.15200309344504995f)   // log2(0.9)
#define RSQRT_DKf   0.17677669529663687f      // 1/sqrt(32)
#define TWO_PIf     6.283185307179586f

typedef __attribute__((ext_vector_type(8))) short bf16x8;
typedef __attribute__((ext_vector_type(4))) float f32x4;

__device__ __forceinline__ short f2bf(float f){
    unsigned u = __float_as_uint(f);
    unsigned r = u + 0x7FFFu + ((u >> 16) & 1u);   // RNE
    return (short)(r >> 16);
}
__device__ __forceinline__ float bf2f(unsigned short s){
    return __uint_as_float(((unsigned)s) << 16);
}

// ---------------- mask (bf16) + loss partials ----------------
__global__ __launch_bounds__(256) void k_mask(const float* __restrict__ lvr,
                       const int* __restrict__ row_idx, const int* __restrict__ col_idx,
                       short* __restrict__ maskb, float* __restrict__ partials)
{
    int idx = blockIdx.x*256 + threadIdx.x;
    unsigned ui = (unsigned)idx;
    int i = ui / S_;
    int j = (int)(ui - (unsigned)i*S_);
    float vr, lm;
    if (i == j) { vr = 0.f; lm = 1.f; }
    else {
        float t = lvr[(size_t)row_idx[idx]*VID_ + col_idx[idx]];
        float sg = 1.f/(1.f + expf(-t));
        vr = sg; lm = sg;
    }
    float dmat = (i >= j) ? exp2f((float)(i-j)*LOG2_GAMMAf) : 0.f;
    maskb[idx] = f2bf(dmat * lm);
    float s = vr;
    #pragma unroll
    for (int m=1; m<64; m<<=1) s += __shfl_xor(s, m, 64);
    __shared__ float ws4[4];
    if ((threadIdx.x & 63) == 0) ws4[threadIdx.x>>6] = s;
    __syncthreads();
    if (threadIdx.x == 0) partials[blockIdx.x] = ws4[0]+ws4[1]+ws4[2]+ws4[3];
}

__global__ __launch_bounds__(256) void k_loss(const float* __restrict__ partials,
                                              float* __restrict__ out_loss)
{
    float s = 0.f;
    for (int i = threadIdx.x; i < SS_/256; i += 256) s += partials[i];
    #pragma unroll
    for (int m=1; m<64; m<<=1) s += __shfl_xor(s, m, 64);
    __shared__ float ws4[4];
    if ((threadIdx.x & 63) == 0) ws4[threadIdx.x>>6] = s;
    __syncthreads();
    if (threadIdx.x == 0) out_loss[0] = (ws4[0]+ws4[1]+ws4[2]+ws4[3]) * (1.f/(float)SS_);
}

// ---------------- weight prep: 6x W -> WT[o][e] bf16, Wout -> bf16 copy ----------------
__global__ __launch_bounds__(256) void k_wprep(
    const float* __restrict__ Wtq, const float* __restrict__ Wtk, const float* __restrict__ Wtv,
    const float* __restrict__ Wvq, const float* __restrict__ Wvk, const float* __restrict__ Wvv,
    const float* __restrict__ Wout, short* __restrict__ WTall, short* __restrict__ WoB)
{
    int seg = blockIdx.x >> 8;
    int r   = blockIdx.x & 255;
    int tid = threadIdx.x;
    if (seg == 6) {
        WoB[r*256 + tid] = f2bf(Wout[r*256 + tid]);
    } else {
        const float* Wsrc = seg==0?Wtq: seg==1?Wtk: seg==2?Wtv: seg==3?Wvq: seg==4?Wvk: Wvv;
        WTall[(size_t)seg*65536 + r*256 + tid] = f2bf(Wsrc[tid*256 + r]);
    }
}

// ---------------- QKV projection via MFMA ----------------
// 16 rows/block, 256 thr. Phase A: transform -> bf16 LDS (swizzled).
// Phase B: Q/K = mfma(WT, X) -> row-major short4 stores; V = mfma(X, WT) -> VT short4.
__global__ __launch_bounds__(256, 2) void k_qkv(const float* __restrict__ src,
    const short* __restrict__ WTq, const short* __restrict__ WTk, const short* __restrict__ WTv,
    short* __restrict__ Qb, short* __restrict__ Kb, short* __restrict__ VT, int is_txt)
{
    __shared__ __align__(16) short xb[3][16][256];   // 24 KB
    __shared__ float invf[128];
    __shared__ float lbs[128];
    int tid = threadIdx.x;
    int r0 = blockIdx.x * 16;
    int b, srow0;
    if (is_txt) { b = r0 >> 5;  srow0 = r0 & 31; }
    else        { b = r0 >> 10; srow0 = TXT_ + (r0 & 1023); }

    if (tid < 128) {
        float fk = (float)tid;
        invf[tid] = exp2f(-fk*(1.f/128.f)*LOG2_10000f);
        lbs[tid]  = log2f((2.f*fk + 102.4f) * (1.f/358.4f));
    }
    __syncthreads();

    #pragma unroll
    for (int it = 0; it < 8; ++it) {
        int task = it*256 + tid;
        int k  = task >> 4;
        int rr = task & 15;
        int srow = srow0 + rr;
        float2 x01 = ((const float2*)(src + ((size_t)b*S_ + srow)*DM_))[k];
        float a0, a1, c0, c1;
        if (is_txt) {
            float xe  = (float)(srow + 1) * (TWO_PIf/(32.f + 1e-6f));
            float arg = xe * invf[k];
            float sn = __sinf(arg), cs = __cosf(arg);
            a0 = x01.x + sn; a1 = x01.y + cs;
            c0 = a0; c1 = a1;
        } else {
            int l = srow - TXT_;
            float arg = (float)l * invf[k];
            float sn = __sinf(arg), cs = __cosf(arg);
            float scale = exp2f((float)l*(1.f/512.f)*lbs[k]);
            float rsc = 1.f/scale;
            float y0 = x01.x*cs - x01.y*sn;
            float y1 = x01.y*cs + x01.x*sn;
            a0 = y0*scale; a1 = y1*scale;
            c0 = y0*rsc;   c1 = y1*rsc;
        }
        int col = (2*k) ^ ((rr&7)<<3);
        *(short2*)&xb[0][rr][col] = make_short2(f2bf(a0), f2bf(a1));
        *(short2*)&xb[1][rr][col] = make_short2(f2bf(c0), f2bf(c1));
        *(short2*)&xb[2][rr][col] = make_short2(f2bf(x01.x), f2bf(x01.y));
    }
    __syncthreads();

    int lane = tid & 63;
    int w    = tid >> 6;
    int lr   = lane & 15;
    int lg   = lane >> 4;
    int swzl = (lr & 7) << 3;

    const short* WTs[3] = {WTq, WTk, WTv};
    #pragma unroll
    for (int m = 0; m < 3; ++m) {
        bf16x8 xf[8];
        #pragma unroll
        for (int kk = 0; kk < 8; ++kk)
            xf[kk] = *(const bf16x8*)&xb[m][lr][(kk*32 + lg*8) ^ swzl];
        #pragma unroll
        for (int ct = 0; ct < 4; ++ct) {
            int tb = (w + ct*4) * 16;
            const short* Wp = WTs[m] + (size_t)(tb+lr)*DM_ + lg*8;
            f32x4 acc = {0.f,0.f,0.f,0.f};
            if (m < 2) {
                #pragma unroll
                for (int kk = 0; kk < 8; ++kk) {
                    bf16x8 wf = *(const bf16x8*)(Wp + kk*32);
                    acc = __builtin_amdgcn_mfma_f32_16x16x32_bf16(wf, xf[kk], acc, 0, 0, 0);
                }
                // D: col(lane&15)=x-row, rows=(lg*4+reg)=o-local -> 4 consecutive o
                int h  = tb >> 5;
                int d0 = (tb & 31) + lg*4;
                size_t off = ((size_t)(b*H_+h)*S_ + srow0+lr)*DK_ + d0;
                short4 s4;
                if (m == 0) {
                    s4.x=f2bf(acc[0]*RSQRT_DKf); s4.y=f2bf(acc[1]*RSQRT_DKf);
                    s4.z=f2bf(acc[2]*RSQRT_DKf); s4.w=f2bf(acc[3]*RSQRT_DKf);
                    *(short4*)&Qb[off] = s4;
                } else {
                    s4.x=f2bf(acc[0]); s4.y=f2bf(acc[1]);
                    s4.z=f2bf(acc[2]); s4.w=f2bf(acc[3]);
                    *(short4*)&Kb[off] = s4;
                }
            } else {
                #pragma unroll
                for (int kk = 0; kk < 8; ++kk) {
                    bf16x8 wf = *(const bf16x8*)(Wp + kk*32);
                    acc = __builtin_amdgcn_mfma_f32_16x16x32_bf16(xf[kk], wf, acc, 0, 0, 0);
                }
                // D: col(lane&15)=o-local, rows=(lg*4+reg)=x-row -> V column = VT row
                int o = tb + lr;
                int h = o >> 5, d = o & 31;
                short4 s4;
                s4.x=f2bf(acc[0]); s4.y=f2bf(acc[1]);
                s4.z=f2bf(acc[2]); s4.w=f2bf(acc[3]);
                *(short4*)&VT[((size_t)(b*H_+h)*DK_ + d)*SP_ + srow0 + lg*4] = s4;
            }
        }
    }
}

// ---------------- kernel A: denominators + ctx (bf16 out) ----------------
#define PH1_STEP(CUR, NXT, TB)                                                          \
    {                                                                                   \
        _Pragma("unroll")                                                               \
        for (int i = 0; i < 4; ++i) {                                                   \
            int tn = (TB) + 4 + i;                                                      \
            if (tn < 16)                                                                \
                NXT[i] = *(const bf16x8*)(Kp + (size_t)tn*64*DK_);                      \
            else if (tn == 16 && w < 2)                                                 \
                NXT[i] = *(const bf16x8*)(Kp + (size_t)16*64*DK_);                      \
        }                                                                               \
        _Pragma("unroll")                                                               \
        for (int i = 0; i < 4; ++i) {                                                   \
            const int t = (TB) + i;                                                     \
            f32x4 acc = {0.f,0.f,0.f,0.f};                                              \
            acc = __builtin_amdgcn_mfma_f32_16x16x32_bf16(CUR[i], qfrag, acc, 0, 0, 0); \
            float e0 = __expf(acc[0]*bf2f(mreg[t].x));                                  \
            float e1 = __expf(acc[1]*bf2f(mreg[t].y));                                  \
            float e2 = __expf(acc[2]*bf2f(mreg[t].z));                                  \
            float e3 = __expf(acc[3]*bf2f(mreg[t].w));                                  \
            rssum += (e0+e1) + (e2+e3);                                                 \
            short4 s4; s4.x=f2bf(e0); s4.y=f2bf(e1); s4.z=f2bf(e2); s4.w=f2bf(e3);      \
            *(short4*)&P[lr][(t*64 + w*16 + lg*4) ^ swq] = s4;                          \
        }                                                                               \
    }

__global__ __launch_bounds__(256, 2) void k_ctx(const short* __restrict__ Qb,
    const short* __restrict__ Kb, const short* __restrict__ VT,
    const short* __restrict__ maskb, short* __restrict__ ctxb, float* __restrict__ denomG)
{
    __shared__ __align__(16) short P[16][SP_];    // 34.0 KB
    __shared__ float rs[2][4][16];
    __shared__ float pv_red[16][36];

    int tid  = threadIdx.x;
    int lane = tid & 63;
    int w    = tid >> 6;
    int b    = blockIdx.x & 15;
    int qt   = blockIdx.x >> 4;
    int q0   = qt * 16;

    int lr = lane & 15;
    int lg = lane >> 4;
    int dh = w & 1;
    int kh = w >> 1;
    int swq = (lr & 7) << 3;

    ushort4 mreg[16];
    const short* mrow = maskb + (size_t)(q0+lr)*S_ + w*16 + lg*4;
    #pragma unroll
    for (int t = 0; t < 16; ++t) mreg[t] = *(const ushort4*)(mrow + t*64);
    ushort4 mtail = make_ushort4(0,0,0,0);
    if (w < 2) mtail = *(const ushort4*)(mrow + 16*64);

    for (int h = 0; h < H_; ++h) {
        const short* Qp = Qb + ((size_t)(b*H_+h)*S_ + q0)*DK_;
        const short* Kp = Kb + (size_t)(b*H_+h)*S_*DK_ + (size_t)(w*16+lr)*DK_ + lg*8;
        bf16x8 qfrag = *(const bf16x8*)(Qp + lr*DK_ + lg*8);

        float rssum = 0.f;
        bf16x8 kfa[4], kfb[4];
        #pragma unroll
        for (int i = 0; i < 4; ++i) kfa[i] = *(const bf16x8*)(Kp + (size_t)i*64*DK_);
        PH1_STEP(kfa, kfb, 0)
        PH1_STEP(kfb, kfa, 4)
        PH1_STEP(kfa, kfb, 8)
        PH1_STEP(kfb, kfa, 12)
        {
            short4 s4; s4.x=0; s4.y=0; s4.z=0; s4.w=0;
            if (w < 2) {
                f32x4 acc = {0.f,0.f,0.f,0.f};
                acc = __builtin_amdgcn_mfma_f32_16x16x32_bf16(kfa[0], qfrag, acc, 0, 0, 0);
                float e0 = __expf(acc[0]*bf2f(mtail.x));
                float e1 = __expf(acc[1]*bf2f(mtail.y));
                float e2 = __expf(acc[2]*bf2f(mtail.z));
                float e3 = __expf(acc[3]*bf2f(mtail.w));
                rssum += (e0+e1) + (e2+e3);
                s4.x=f2bf(e0); s4.y=f2bf(e1); s4.z=f2bf(e2); s4.w=f2bf(e3);
            }
            *(short4*)&P[lr][(1024 + w*16 + lg*4) ^ swq] = s4;
        }
        rssum += __shfl_xor(rssum, 16, 64);
        rssum += __shfl_xor(rssum, 32, 64);
        if (lane < 16) rs[h&1][w][lr] = rssum;
        __syncthreads();
        if (tid < 16) {
            float rd = 1.f/(rs[h&1][0][tid]+rs[h&1][1][tid]+rs[h&1][2][tid]+rs[h&1][3][tid]);
            denomG[(size_t)(b*H_+h)*S_ + q0 + tid] = rd;
        }

        const short* Vp = VT + ((size_t)(b*H_+h)*DK_ + dh*16 + lr)*SP_ + lg*8;
        int kbase = kh * 17 * 32;
        f32x4 pv0 = {0.f,0.f,0.f,0.f}, pv1 = {0.f,0.f,0.f,0.f};
        #pragma unroll
        for (int u = 0; u < 8; ++u) {
            int kbA = kbase + (2*u  )*32;
            int kbB = kbase + (2*u+1)*32;
            bf16x8 pfA = *(const bf16x8*)&P[lr][(kbA + lg*8) ^ swq];
            bf16x8 vfA = *(const bf16x8*)(Vp + kbA);
            bf16x8 pfB = *(const bf16x8*)&P[lr][(kbB + lg*8) ^ swq];
            bf16x8 vfB = *(const bf16x8*)(Vp + kbB);
            pv0 = __builtin_amdgcn_mfma_f32_16x16x32_bf16(pfA, vfA, pv0, 0, 0, 0);
            pv1 = __builtin_amdgcn_mfma_f32_16x16x32_bf16(pfB, vfB, pv1, 0, 0, 0);
        }
        {
            int kb = kbase + 16*32;
            bf16x8 pf = *(const bf16x8*)&P[lr][(kb + lg*8) ^ swq];
            bf16x8 vf = *(const bf16x8*)(Vp + kb);
            pv0 = __builtin_amdgcn_mfma_f32_16x16x32_bf16(pf, vf, pv0, 0, 0, 0);
        }
        f32x4 pvacc;
        pvacc[0]=pv0[0]+pv1[0]; pvacc[1]=pv0[1]+pv1[1];
        pvacc[2]=pv0[2]+pv1[2]; pvacc[3]=pv0[3]+pv1[3];

        if (kh == 1) {
            #pragma unroll
            for (int r = 0; r < 4; ++r) pv_red[lg*4+r][dh*16+lr] = pvacc[r];
        }
        __syncthreads();
        if (kh == 0) {
            #pragma unroll
            for (int r = 0; r < 4; ++r) {
                int qq = lg*4 + r;
                float rd = 1.f/(rs[h&1][0][qq]+rs[h&1][1][qq]+rs[h&1][2][qq]+rs[h&1][3][qq]);
                float v = pvacc[r] + pv_red[qq][dh*16+lr];
                ctxb[((size_t)b*S_ + q0+qq)*DM_ + h*DK_ + dh*16 + lr] = f2bf(v * rd);
            }
        }
    }
}

// ---------------- kernel B: att by score recompute ----------------
__global__ __launch_bounds__(256, 2) void k_att(const short* __restrict__ Qb,
    const short* __restrict__ Kb, const short* __restrict__ maskb,
    const float* __restrict__ denomG, float* __restrict__ att)
{
    __shared__ float rd_l[8][16];
    int tid  = threadIdx.x;
    int lane = tid & 63;
    int w    = tid >> 6;
    int b    = blockIdx.x & 15;
    int qt   = blockIdx.x >> 4;
    int q0   = qt * 16;

    if (tid < 128)
        rd_l[tid>>4][tid&15] = denomG[(size_t)(b*H_+(tid>>4))*S_ + q0 + (tid&15)] * 0.125f;
    __syncthreads();

    int lr = lane & 15;
    int lg = lane >> 4;

    bf16x8 qf[8];
    #pragma unroll
    for (int h = 0; h < 8; ++h)
        qf[h] = *(const bf16x8*)(Qb + ((size_t)(b*H_+h)*S_ + q0+lr)*DK_ + lg*8);

    const size_t kstride = (size_t)S_*DK_;
    const short* Kbase = Kb + (size_t)b*H_*kstride + lg*8;

    int nt = (w < 2) ? 17 : 16;
    for (int t = 0; t < nt; ++t) {
        int k0 = t*64 + w*16;
        float m0 = bf2f((unsigned short)maskb[(size_t)(q0+4*lg+0)*S_ + k0+lr]);
        float m1 = bf2f((unsigned short)maskb[(size_t)(q0+4*lg+1)*S_ + k0+lr]);
        float m2 = bf2f((unsigned short)maskb[(size_t)(q0+4*lg+2)*S_ + k0+lr]);
        float m3 = bf2f((unsigned short)maskb[(size_t)(q0+4*lg+3)*S_ + k0+lr]);
        f32x4 a = {0.f,0.f,0.f,0.f};
        #pragma unroll
        for (int h = 0; h < 8; ++h) {
            bf16x8 kfrag = *(const bf16x8*)(Kbase + (size_t)h*kstride + (size_t)(k0+lr)*DK_);
            f32x4 s = {0.f,0.f,0.f,0.f};
            s = __builtin_amdgcn_mfma_f32_16x16x32_bf16(qf[h], kfrag, s, 0, 0, 0);
            a[0] = fmaf(__expf(s[0]*m0), rd_l[h][4*lg+0], a[0]);
            a[1] = fmaf(__expf(s[1]*m1), rd_l[h][4*lg+1], a[1]);
            a[2] = fmaf(__expf(s[2]*m2), rd_l[h][4*lg+2], a[2]);
            a[3] = fmaf(__expf(s[3]*m3), rd_l[h][4*lg+3], a[3]);
        }
        att[((size_t)b*S_ + q0+4*lg+0)*S_ + k0+lr] = a[0];
        att[((size_t)b*S_ + q0+4*lg+1)*S_ + k0+lr] = a[1];
        att[((size_t)b*S_ + q0+4*lg+2)*S_ + k0+lr] = a[2];
        att[((size_t)b*S_ + q0+4*lg+3)*S_ + k0+lr] = a[3];
    }
}

// ---------------- out projection via MFMA (no LDS) ----------------
__global__ __launch_bounds__(256, 2) void k_outproj(const short* __restrict__ ctxb,
    const short* __restrict__ WoB, const float* __restrict__ bias, float* __restrict__ out)
{
    int tid  = threadIdx.x;
    int lane = tid & 63;
    int w    = tid >> 6;
    int lr   = lane & 15;
    int lg   = lane >> 4;
    int r0   = blockIdx.x * 16;

    bf16x8 cf[8];
    #pragma unroll
    for (int kk = 0; kk < 8; ++kk)
        cf[kk] = *(const bf16x8*)(ctxb + (size_t)(r0+lr)*DM_ + kk*32 + lg*8);

    #pragma unroll
    for (int ct = 0; ct < 4; ++ct) {
        int tb = (w + ct*4) * 16;
        const short* Wp = WoB + (size_t)(tb+lr)*DM_ + lg*8;
        f32x4 acc = {0.f,0.f,0.f,0.f};
        #pragma unroll
        for (int kk = 0; kk < 8; ++kk) {
            bf16x8 wf = *(const bf16x8*)(Wp + kk*32);
            acc = __builtin_amdgcn_mfma_f32_16x16x32_bf16(wf, cf[kk], acc, 0, 0, 0);
        }
        float4 b4 = *(const float4*)&bias[tb + lg*4];
        float4 o4 = make_float4(acc[0]+b4.x, acc[1]+b4.y, acc[2]+b4.z, acc[3]+b4.w);
        *(float4*)&out[(size_t)(r0+lr)*DM_ + tb + lg*4] = o4;
    }
}

extern "C" void kernel_launch(void* const* d_in, const int* in_sizes, int n_in,
                              void* d_out, int out_size, void* d_ws, size_t ws_size,
                              hipStream_t stream)
{
    (void)in_sizes; (void)n_in; (void)out_size; (void)ws_size;
    const float* src  = (const float*)d_in[0];
    const float* Wtq  = (const float*)d_in[1];
    const float* Wtk  = (const float*)d_in[2];
    const float* Wtv  = (const float*)d_in[3];
    const float* Wvq  = (const float*)d_in[4];
    const float* Wvk  = (const float*)d_in[5];
    const float* Wvv  = (const float*)d_in[6];
    const float* lvr  = (const float*)d_in[7];
    const float* Wout = (const float*)d_in[8];
    const float* bout = (const float*)d_in[9];
    const int*   rid  = (const int*)d_in[10];
    const int*   cid  = (const int*)d_in[11];

    const size_t QKV_SH = (size_t)B_*H_*S_*DK_;    // shorts per Q/K buffer
    const size_t VT_SH  = (size_t)B_*H_*DK_*SP_;   // shorts for V^T
    const size_t CTX_SH = (size_t)B_*S_*DM_;

    float* ws       = (float*)d_ws;
    float* partials = ws;                           // 4356
    float* denomG   = partials + 4356;              // B*H*S
    short* maskb    = (short*)(denomG + (size_t)B_*H_*S_);
    short* Qb       = maskb + SS_;
    short* Kb       = Qb + QKV_SH;
    short* VT       = Kb + QKV_SH;
    short* ctxb     = VT + VT_SH;
    short* WTall    = ctxb + CTX_SH;                // 6*65536
    short* WoB      = WTall + 6*65536;

    float* out  = (float*)d_out;
    float* att  = out + (size_t)B_*S_*DM_;
    float* loss = att + (size_t)B_*S_*S_;

    k_mask<<<SS_/256, 256, 0, stream>>>(lvr, rid, cid, maskb, partials);
    k_wprep<<<7*256, 256, 0, stream>>>(Wtq, Wtk, Wtv, Wvq, Wvk, Wvv, Wout, WTall, WoB);
    k_qkv<<<(B_*TXT_)/16, 256, 0, stream>>>(src, WTall, WTall+65536, WTall+2*65536,
                                            Qb, Kb, VT, 1);
    k_qkv<<<(B_*VID_)/16, 256, 0, stream>>>(src, WTall+3*65536, WTall+4*65536, WTall+5*65536,
                                            Qb, Kb, VT, 0);
    k_ctx<<<B_*NQT_, 256, 0, stream>>>(Qb, Kb, VT, maskb, ctxb, denomG);
    k_att<<<B_*NQT_, 256, 0, stream>>>(Qb, Kb, maskb, denomG, att);
    k_outproj<<<(B_*S_)/16, 256, 0, stream>>>(ctxb, WoB, bout, out);
    k_loss<<<1, 256, 0, stream>>>(partials, loss);
}